// Round 4
// baseline (208.595 us; speedup 1.0000x reference)
//
#include <hip/hip_runtime.h>

#define N_BINS 30
#define NCLASS 10
#define BLOCK 256
#define GRID 2048          // 8 blocks/CU * 256 CU

// ECE = sum_b | sum_{i in bin b} (conf_i - acc_i) | / N   (counts cancel)
// Workspace: 30 x i64 (two's-complement in u64) fixed-point sums (2^20 scale)
//            + 1 u32 done-counter. Zeroed by hipMemsetAsync each call.

__global__ __launch_bounds__(BLOCK) void ece_hist(
        const float* __restrict__ sm,
        const int*   __restrict__ labels,
        int n,
        unsigned long long* __restrict__ g_sum,
        unsigned int* __restrict__ done,
        float* __restrict__ out) {
    // 30 per-thread accumulators, fully static indexing -> VGPRs (rule #20)
    float acc[N_BINS];
    #pragma unroll
    for (int b = 0; b < N_BINS; ++b) acc[b] = 0.0f;

    const int tid = threadIdx.x;
    const int gsize = GRID * BLOCK;

    for (int r = blockIdx.x * BLOCK + tid; r < n; r += gsize) {
        const float* row = sm + (long long)r * NCLASS;
        float2 q0 = *reinterpret_cast<const float2*>(row + 0);
        float2 q1 = *reinterpret_cast<const float2*>(row + 2);
        float2 q2 = *reinterpret_cast<const float2*>(row + 4);
        float2 q3 = *reinterpret_cast<const float2*>(row + 6);
        float2 q4 = *reinterpret_cast<const float2*>(row + 8);
        int lbl = labels[r];

        float v[NCLASS] = {q0.x, q0.y, q1.x, q1.y, q2.x,
                           q2.y, q3.x, q3.y, q4.x, q4.y};
        float conf = v[0];
        int pred = 0;
        #pragma unroll
        for (int j = 1; j < NCLASS; ++j)
            if (v[j] > conf) { conf = v[j]; pred = j; }   // first-max, matches argmax

        int bin = min(max((int)ceilf(conf * 30.0f) - 1, 0), N_BINS - 1);
        float d = conf - ((pred == lbl) ? 1.0f : 0.0f);

        #pragma unroll
        for (int b = 0; b < N_BINS; ++b)
            acc[b] += (bin == b) ? d : 0.0f;              // predicated, no atomics
    }

    // ---- once-per-kernel reduction ----
    #pragma unroll
    for (int b = 0; b < N_BINS; ++b) {
        float s = acc[b];
        s += __shfl_xor(s, 1);
        s += __shfl_xor(s, 2);
        s += __shfl_xor(s, 4);
        s += __shfl_xor(s, 8);
        s += __shfl_xor(s, 16);
        s += __shfl_xor(s, 32);
        acc[b] = s;
    }

    __shared__ float s_part[4][N_BINS];
    __shared__ unsigned int s_last;
    const int lane = tid & 63;
    const int wid  = tid >> 6;
    if (lane == 0) {
        #pragma unroll
        for (int b = 0; b < N_BINS; ++b) s_part[wid][b] = acc[b];
    }
    __syncthreads();

    if (tid < N_BINS) {
        float s = s_part[0][tid] + s_part[1][tid] + s_part[2][tid] + s_part[3][tid];
        long long fx = (long long)llrintf(s * 1048576.0f);   // 2^20 fixed point
        atomicAdd(&g_sum[tid], (unsigned long long)fx);      // integer: order-independent
    }
    __threadfence();
    __syncthreads();

    if (tid == 0)
        s_last = (atomicAdd(done, 1u) == GRID - 1) ? 1u : 0u;
    __syncthreads();

    if (s_last && tid == 0) {
        __threadfence();
        double total = 0.0;
        #pragma unroll
        for (int b = 0; b < N_BINS; ++b) {
            long long v = (long long)atomicAdd(&g_sum[b], 0ull);  // coherent read
            total += fabs((double)v);
        }
        out[0] = (float)(total * (1.0 / 1048576.0) / (double)n);
    }
}

extern "C" void kernel_launch(void* const* d_in, const int* in_sizes, int n_in,
                              void* d_out, int out_size, void* d_ws, size_t ws_size,
                              hipStream_t stream) {
    const float* sm   = (const float*)d_in[0];
    const int* labels = (const int*)d_in[1];
    const int n = in_sizes[1];   // 4,000,000 rows

    unsigned long long* g_sum = (unsigned long long*)d_ws;
    unsigned int* done = (unsigned int*)(g_sum + N_BINS);

    hipMemsetAsync(d_ws, 0, N_BINS * sizeof(unsigned long long) + sizeof(unsigned int),
                   stream);
    ece_hist<<<GRID, BLOCK, 0, stream>>>(sm, labels, n, g_sum, done,
                                         (float*)d_out);
}

// Round 5
// 166.504 us; speedup vs baseline: 1.2528x; 1.2528x over previous
//
#include <hip/hip_runtime.h>

#define N_BINS 30
#define BLOCK 256
#define GRID 2048          // 8 blocks/CU * 256 CU

// ECE = sum_b | sum_{i in bin b} (conf_i - acc_i) | / N   (counts cancel).
// Per-thread: 30 NAMED scalar accumulators (macro-expanded) -> guaranteed VGPRs
// (R4's float acc[30] was demoted to scratch: VGPR=36, 60 scratch ops/row).
// Workspace: 30 x i64 fixed-point (2^20) sums + 1 u32 done counter.

#define FOR_BINS(X) \
  X(0) X(1) X(2) X(3) X(4) X(5) X(6) X(7) X(8) X(9) \
  X(10) X(11) X(12) X(13) X(14) X(15) X(16) X(17) X(18) X(19) \
  X(20) X(21) X(22) X(23) X(24) X(25) X(26) X(27) X(28) X(29)

__global__ __launch_bounds__(BLOCK) void ece_hist(
        const float* __restrict__ sm,
        const int*   __restrict__ labels,
        int n,
        unsigned long long* __restrict__ g_sum,
        unsigned int* __restrict__ done,
        float* __restrict__ out) {
#define DECL_ACC(b) float acc##b = 0.0f;
    FOR_BINS(DECL_ACC)

    const int tid = threadIdx.x;

    for (int r = blockIdx.x * BLOCK + tid; r < n; r += GRID * BLOCK) {
        const float* row = sm + (long long)r * 10;
        float2 q0 = *reinterpret_cast<const float2*>(row + 0);
        float2 q1 = *reinterpret_cast<const float2*>(row + 2);
        float2 q2 = *reinterpret_cast<const float2*>(row + 4);
        float2 q3 = *reinterpret_cast<const float2*>(row + 6);
        float2 q4 = *reinterpret_cast<const float2*>(row + 8);
        int lbl = labels[r];

        // first-occurrence argmax (strict >), no arrays
        float conf = q0.x; int pred = 0;
        if (q0.y > conf) { conf = q0.y; pred = 1; }
        if (q1.x > conf) { conf = q1.x; pred = 2; }
        if (q1.y > conf) { conf = q1.y; pred = 3; }
        if (q2.x > conf) { conf = q2.x; pred = 4; }
        if (q2.y > conf) { conf = q2.y; pred = 5; }
        if (q3.x > conf) { conf = q3.x; pred = 6; }
        if (q3.y > conf) { conf = q3.y; pred = 7; }
        if (q4.x > conf) { conf = q4.x; pred = 8; }
        if (q4.y > conf) { conf = q4.y; pred = 9; }

        int bin = min(max((int)ceilf(conf * 30.0f) - 1, 0), N_BINS - 1);
        float d = conf - ((pred == lbl) ? 1.0f : 0.0f);

#define UPD_ACC(b) acc##b += (bin == (b)) ? d : 0.0f;
        FOR_BINS(UPD_ACC)
    }

    // ---- once-per-kernel reduction: 64-lane butterfly per bin ----
    __shared__ float s_part[4][N_BINS];
    __shared__ unsigned int s_last;
    const int lane = tid & 63;
    const int wid  = tid >> 6;

#define RED_ACC(b) { \
    float s = acc##b; \
    s += __shfl_xor(s, 1);  s += __shfl_xor(s, 2);  s += __shfl_xor(s, 4); \
    s += __shfl_xor(s, 8);  s += __shfl_xor(s, 16); s += __shfl_xor(s, 32); \
    if (lane == 0) s_part[wid][b] = s; }
    FOR_BINS(RED_ACC)
    __syncthreads();

    if (tid < N_BINS) {
        float s = s_part[0][tid] + s_part[1][tid] + s_part[2][tid] + s_part[3][tid];
        long long fx = (long long)llrintf(s * 1048576.0f);   // 2^20 fixed point
        atomicAdd(&g_sum[tid], (unsigned long long)fx);      // integer: order-independent
    }
    __threadfence();
    __syncthreads();

    if (tid == 0)
        s_last = (atomicAdd(done, 1u) == GRID - 1) ? 1u : 0u;
    __syncthreads();

    if (s_last && tid == 0) {
        __threadfence();
        double total = 0.0;
        for (int b = 0; b < N_BINS; ++b) {
            long long v = (long long)atomicAdd(&g_sum[b], 0ull);  // coherent read
            total += fabs((double)v);
        }
        out[0] = (float)(total * (1.0 / 1048576.0) / (double)n);
    }
}

extern "C" void kernel_launch(void* const* d_in, const int* in_sizes, int n_in,
                              void* d_out, int out_size, void* d_ws, size_t ws_size,
                              hipStream_t stream) {
    const float* sm   = (const float*)d_in[0];
    const int* labels = (const int*)d_in[1];
    const int n = in_sizes[1];   // 4,000,000 rows

    unsigned long long* g_sum = (unsigned long long*)d_ws;
    unsigned int* done = (unsigned int*)(g_sum + N_BINS);

    hipMemsetAsync(d_ws, 0,
                   N_BINS * sizeof(unsigned long long) + sizeof(unsigned int),
                   stream);
    ece_hist<<<GRID, BLOCK, 0, stream>>>(sm, labels, n, g_sum, done,
                                         (float*)d_out);
}